// Round 1
// baseline (2558.273 us; speedup 1.0000x reference)
//
#include <hip/hip_runtime.h>
#include <hip/hip_bf16.h>
#include <math.h>

#define HDIM 128
#define T3   384
#define NT   2048
#define NBND 512
#define NLEN 65536

__device__ __forceinline__ float sigmoidf_(float x){ return 1.f/(1.f+__expf(-x)); }
__device__ __forceinline__ float tanhf_(float x){ float e=__expf(2.f*x); return 1.f - 2.f/(e+1.f); }

// ---------------------------------------------------------------- in-MLPs
// per (b,t): h0 = lrelu(LN(cp0*W0+b0)), h1 likewise -> hcat[bt][256]
__global__ __launch_bounds__(128) void k_inmlp(
    const float* __restrict__ cp0, const float* __restrict__ cp1,
    const float* __restrict__ W0, const float* __restrict__ b0,
    const float* __restrict__ g0, const float* __restrict__ be0,
    const float* __restrict__ W1, const float* __restrict__ b1,
    const float* __restrict__ g1, const float* __restrict__ be1,
    float* __restrict__ hcat)
{
  int bt = blockIdx.x; int i = threadIdx.x;
  float c0 = cp0[bt], c1 = cp1[bt];
  float v0 = fmaf(c0, W0[i], b0[i]);
  float v1 = fmaf(c1, W1[i], b1[i]);
  __shared__ float red[4];
  float s0 = v0, s1 = v1;
  #pragma unroll
  for (int m=1;m<64;m<<=1){ s0 += __shfl_xor(s0,m); s1 += __shfl_xor(s1,m); }
  if ((i&63)==0){ red[(i>>6)*2+0]=s0; red[(i>>6)*2+1]=s1; }
  __syncthreads();
  float m0 = (red[0]+red[2])*(1.f/128.f);
  float m1 = (red[1]+red[3])*(1.f/128.f);
  __syncthreads();
  float d0 = v0-m0, d1 = v1-m1;
  float q0 = d0*d0, q1 = d1*d1;
  #pragma unroll
  for (int m=1;m<64;m<<=1){ q0 += __shfl_xor(q0,m); q1 += __shfl_xor(q1,m); }
  if ((i&63)==0){ red[(i>>6)*2+0]=q0; red[(i>>6)*2+1]=q1; }
  __syncthreads();
  float va0 = (red[0]+red[2])*(1.f/128.f);
  float va1 = (red[1]+red[3])*(1.f/128.f);
  float y0 = d0*rsqrtf(va0+1e-5f)*g0[i] + be0[i];
  float y1 = d1*rsqrtf(va1+1e-5f)*g1[i] + be1[i];
  y0 = y0>=0.f ? y0 : 0.01f*y0;
  y1 = y1>=0.f ? y1 : 0.01f*y1;
  hcat[(size_t)bt*256 + i]       = y0;
  hcat[(size_t)bt*256 + 128 + i] = y1;
}

// ---------------------------------------------------------------- xp GEMM
// xp[4096][384] = hcat[4096][256] @ Wih^T[256][384] + bih
__global__ __launch_bounds__(256) void k_xp(
    const float* __restrict__ hcat, const float* __restrict__ Wih,
    const float* __restrict__ bih, float* __restrict__ xp)
{
  __shared__ float ht[32][257];
  __shared__ float wT[256][97];
  int mb = blockIdx.x;      // 0..127
  int nbt = blockIdx.y;     // 0..3
  int tid = threadIdx.x;
  int row0 = mb*32, g0 = nbt*96;
  for (int idx = tid; idx < 32*256; idx += 256){
    int t = idx >> 8, k = idx & 255;
    ht[t][k] = hcat[(size_t)(row0+t)*256 + k];
  }
  for (int idx = tid; idx < 96*256; idx += 256){
    int g = idx >> 8, k = idx & 255;
    wT[k][g] = Wih[(size_t)(g0+g)*256 + k];
  }
  __syncthreads();
  int tt = tid & 7;    // t within group-of-8
  int gg = tid >> 3;   // 0..31, 3 outputs each
  float a00=0,a01=0,a02=0, a10=0,a11=0,a12=0, a20=0,a21=0,a22=0, a30=0,a31=0,a32=0;
  for (int k=0;k<256;k++){
    float h0 = ht[tt][k], h1 = ht[tt+8][k], h2 = ht[tt+16][k], h3 = ht[tt+24][k];
    float w0 = wT[k][gg*3+0], w1 = wT[k][gg*3+1], w2 = wT[k][gg*3+2];
    a00 = fmaf(h0,w0,a00); a01 = fmaf(h0,w1,a01); a02 = fmaf(h0,w2,a02);
    a10 = fmaf(h1,w0,a10); a11 = fmaf(h1,w1,a11); a12 = fmaf(h1,w2,a12);
    a20 = fmaf(h2,w0,a20); a21 = fmaf(h2,w1,a21); a22 = fmaf(h2,w2,a22);
    a30 = fmaf(h3,w0,a30); a31 = fmaf(h3,w1,a31); a32 = fmaf(h3,w2,a32);
  }
  float accs[4][3] = {{a00,a01,a02},{a10,a11,a12},{a20,a21,a22},{a30,a31,a32}};
  #pragma unroll
  for (int ti=0;ti<4;ti++){
    int row = row0 + tt + 8*ti;
    #pragma unroll
    for (int gi=0;gi<3;gi++){
      int g = g0 + gg*3 + gi;
      xp[(size_t)row*T3 + g] = accs[ti][gi] + bih[g];
    }
  }
}

// ---------------------------------------------------------------- GRU scan
// 2 blocks (one per batch), 768 threads: thread = (row j<384, K-half kh).
// W_hh row-half lives in VGPRs; h broadcast from LDS; 2 barriers/step.
__global__ __launch_bounds__(768,1) void k_gru(
    const float* __restrict__ xp, const float* __restrict__ Whh,
    const float* __restrict__ bhh, float* __restrict__ hout)
{
  __shared__ float hbuf[128];
  __shared__ float gsc[384];
  int b = blockIdx.x;
  int tid = threadIdx.x;
  int j = tid >> 1, kh = tid & 1;
  float2 w[32];
  const float2* wr = (const float2*)(Whh + j*128 + kh*64);
  #pragma unroll
  for (int i=0;i<32;i++) w[i] = wr[i];
  float bj = (kh==0) ? bhh[j] : 0.f;
  if (tid < 128) hbuf[tid] = 0.f;
  __syncthreads();
  const float* xpb = xp + (size_t)b*NT*T3;
  float* hob = hout + (size_t)b*NT*HDIM;
  const float2* h2base = (const float2*)(hbuf + kh*64);
  for (int t=0;t<NT;t++){
    float xr=0.f, xz=0.f, xn=0.f, hprev=0.f;
    if (tid < 128){
      const float* xq = xpb + (size_t)t*T3;
      xr = xq[tid]; xz = xq[128+tid]; xn = xq[256+tid];
      hprev = hbuf[tid];
    }
    float2 a0 = {0.f,0.f}, a1 = {0.f,0.f};
    #pragma unroll
    for (int i=0;i<32;i+=2){
      float2 hv0 = h2base[i], hv1 = h2base[i+1];
      a0.x = fmaf(w[i].x,   hv0.x, a0.x);
      a0.y = fmaf(w[i].y,   hv0.y, a0.y);
      a1.x = fmaf(w[i+1].x, hv1.x, a1.x);
      a1.y = fmaf(w[i+1].y, hv1.y, a1.y);
    }
    float acc = (a0.x+a0.y) + (a1.x+a1.y);
    acc += __shfl_xor(acc, 1);
    if (kh == 0) gsc[j] = acc + bj;
    __syncthreads();
    if (tid < 128){
      float r = sigmoidf_(xr + gsc[tid]);
      float z = sigmoidf_(xz + gsc[128+tid]);
      float n = tanhf_(fmaf(r, gsc[256+tid], xn));
      float hn = fmaf(z, hprev - n, n);       // (1-z)n + z*h
      hbuf[tid] = hn;
      hob[(size_t)t*HDIM + tid] = hn;
    }
    __syncthreads();
  }
}

// ---------------------------------------------------------------- post MLPs + amp
// per block: 16 t's. 3x (Linear->LN->lrelu) then amp Linear + scale fn.
__global__ __launch_bounds__(256) void k_post(
    const float* __restrict__ hout, const float* __restrict__ cp0, const float* __restrict__ cp1,
    const float* __restrict__ o0W, const float* __restrict__ o0b, const float* __restrict__ o0g, const float* __restrict__ o0be,
    const float* __restrict__ o1W, const float* __restrict__ o1b, const float* __restrict__ o1g, const float* __restrict__ o1be,
    const float* __restrict__ o2W, const float* __restrict__ o2b, const float* __restrict__ o2g, const float* __restrict__ o2be,
    const float* __restrict__ ampW, const float* __restrict__ ampb,
    float* __restrict__ amps)
{
  __shared__ float bufA[16][132];
  __shared__ float bufB[16][132];
  __shared__ float wT[130*129];
  __shared__ float red2[2][2];
  int blk = blockIdx.x;
  int b = blk >> 7, tc = blk & 127;
  int bt0 = b*NT + tc*16;
  int tid = threadIdx.x;
  for (int idx = tid; idx < 16*130; idx += 256){
    int t = idx / 130, k = idx - t*130;
    int bt = bt0 + t;
    float v;
    if (k < 128)      v = hout[(size_t)bt*HDIM + k];
    else if (k==128)  v = cp0[bt];
    else              v = cp1[bt];
    bufA[t][k] = v;
  }
  __syncthreads();
  const float* Ws[3] = {o0W, o1W, o2W};
  const float* Bs[3] = {o0b, o1b, o2b};
  const float* Gs[3] = {o0g, o1g, o2g};
  const float* Es[3] = {o0be, o1be, o2be};
  float (*src)[132] = bufA;
  float (*dst)[132] = bufB;
  int kd = 130;
  int i  = tid & 127, th = tid >> 7;
  int wv = (tid>>6)&1;
  for (int l=0; l<3; l++){
    const float* W = Ws[l];
    for (int idx = tid; idx < 128*kd; idx += 256){
      int o = idx / kd, k = idx - o*kd;
      wT[k*129 + o] = W[idx];
    }
    __syncthreads();
    float bi = Bs[l][i], gi = Gs[l][i], ei = Es[l][i];
    for (int tp=0; tp<16; tp+=2){
      int t = tp + th;
      float acc0 = bi, acc1 = 0.f;
      for (int k=0;k<kd;k+=2){
        acc0 = fmaf(wT[k*129+i],     src[t][k],   acc0);
        acc1 = fmaf(wT[(k+1)*129+i], src[t][k+1], acc1);
      }
      float acc = acc0 + acc1;
      float s = acc;
      #pragma unroll
      for (int m=1;m<64;m<<=1) s += __shfl_xor(s,m);
      if ((tid&63)==0) red2[th][wv] = s;
      __syncthreads();
      float mean = (red2[th][0]+red2[th][1])*(1.f/128.f);
      __syncthreads();
      float d = acc - mean, q = d*d;
      #pragma unroll
      for (int m=1;m<64;m<<=1) q += __shfl_xor(q,m);
      if ((tid&63)==0) red2[th][wv] = q;
      __syncthreads();
      float var = (red2[th][0]+red2[th][1])*(1.f/128.f);
      float y = d*rsqrtf(var+1e-5f)*gi + ei;
      y = y>=0.f ? y : 0.01f*y;
      dst[t][i] = y;
      __syncthreads();
    }
    { float (*tmp)[132] = src; src = dst; dst = tmp; }
    kd = 128;
    __syncthreads();
  }
  // amp projection 128 -> 512 in 4 chunks + scale function
  for (int ch=0; ch<4; ch++){
    for (int idx = tid; idx < 128*128; idx += 256){
      int o = idx >> 7, k = idx & 127;
      wT[k*129 + o] = ampW[(size_t)(ch*128+o)*128 + k];
    }
    __syncthreads();
    float bi = ampb[ch*128 + i];
    for (int tp=0; tp<16; tp+=2){
      int t = tp + th;
      float acc0 = bi, acc1 = 0.f;
      for (int k=0;k<128;k+=2){
        acc0 = fmaf(wT[k*129+i],     src[t][k],   acc0);
        acc1 = fmaf(wT[(k+1)*129+i], src[t][k+1], acc1);
      }
      float acc = acc0 + acc1;
      float sg = sigmoidf_(acc);
      float p = __powf(sg, 2.3025850929940457f);  // sigmoid^ln(10)
      amps[(size_t)(bt0+t)*NBND + ch*128 + i] = 2.f*p + 1e-18f;
    }
    __syncthreads();
  }
}

// ---------------------------------------------------------------- synth mixdown
// out[b][s] = sum_c ( a[b,c,i0]*(1-w) + a[b,c,i1]*w ) * nb[c,s]
__global__ __launch_bounds__(256) void k_synth(
    const float* __restrict__ amps, const float* __restrict__ nbands,
    float* __restrict__ out)
{
  __shared__ float SA[2*10*516];   // [b][10 frames][516-padded bands]
  int blk = blockIdx.x;
  int tid = threadIdx.x;
  int s = blk*256 + tid;
  int tbase = blk*8 - 1; if (tbase < 0) tbase = 0;
  for (int idx = tid; idx < 2*10*512; idx += 256){
    int bb  = idx / 5120;
    int rem = idx - bb*5120;
    int ttl = rem >> 9;
    int c   = rem & 511;
    int tg = tbase + ttl; if (tg > NT-1) tg = NT-1;
    SA[bb*5160 + ttl*516 + c] = amps[(size_t)(bb*NT + tg)*NBND + c];
  }
  __syncthreads();
  float srcp = fmaxf((s + 0.5f)*(1.f/32.f) - 0.5f, 0.f);
  int i0 = (int)srcp;                 // floor (non-negative)
  float w = srcp - (float)i0;
  int i1 = i0 + 1; if (i1 > NT-1) i1 = NT-1;
  int l0 = i0 - tbase, l1 = i1 - tbase;
  float um = 1.f - w;
  const float* A0 = SA + l0*516;
  const float* A1 = SA + l1*516;
  const float* B0 = SA + 5160 + l0*516;
  const float* B1 = SA + 5160 + l1*516;
  float acc0 = 0.f, acc1 = 0.f;
  for (int c=0;c<NBND;c++){
    float nv = nbands[(size_t)c*NLEN + s];
    float u0 = um*A0[c] + w*A1[c];
    float u1 = um*B0[c] + w*B1[c];
    acc0 = fmaf(u0, nv, acc0);
    acc1 = fmaf(u1, nv, acc1);
  }
  out[s]        = acc0;
  out[NLEN + s] = acc1;
}

// ----------------------------------------------------------------
extern "C" void kernel_launch(void* const* d_in, const int* in_sizes, int n_in,
                              void* d_out, int out_size, void* d_ws, size_t ws_size,
                              hipStream_t stream)
{
  const float* cp0   = (const float*)d_in[0];
  const float* cp1   = (const float*)d_in[1];
  const float* in0W  = (const float*)d_in[2];
  const float* in0b  = (const float*)d_in[3];
  const float* in0g  = (const float*)d_in[4];
  const float* in0be = (const float*)d_in[5];
  const float* in1W  = (const float*)d_in[6];
  const float* in1b  = (const float*)d_in[7];
  const float* in1g  = (const float*)d_in[8];
  const float* in1be = (const float*)d_in[9];
  const float* Wih   = (const float*)d_in[10];
  const float* Whh   = (const float*)d_in[11];
  const float* bih   = (const float*)d_in[12];
  const float* bhh   = (const float*)d_in[13];
  const float* o0W = (const float*)d_in[14]; const float* o0b = (const float*)d_in[15];
  const float* o0g = (const float*)d_in[16]; const float* o0be = (const float*)d_in[17];
  const float* o1W = (const float*)d_in[18]; const float* o1b = (const float*)d_in[19];
  const float* o1g = (const float*)d_in[20]; const float* o1be = (const float*)d_in[21];
  const float* o2W = (const float*)d_in[22]; const float* o2b = (const float*)d_in[23];
  const float* o2g = (const float*)d_in[24]; const float* o2be = (const float*)d_in[25];
  const float* ampW = (const float*)d_in[26];
  const float* ampb = (const float*)d_in[27];
  const float* nbnd = (const float*)d_in[28];

  float* ws   = (float*)d_ws;
  float* hcat = ws;                       // 4096*256
  float* xp   = hcat + 4096*256;          // 4096*384
  float* hout = xp   + 4096*384;          // 4096*128
  float* amps = hout + 4096*128;          // 4096*512

  k_inmlp<<<dim3(4096), dim3(128), 0, stream>>>(cp0, cp1, in0W, in0b, in0g, in0be,
                                                in1W, in1b, in1g, in1be, hcat);
  k_xp<<<dim3(128,4), dim3(256), 0, stream>>>(hcat, Wih, bih, xp);
  k_gru<<<dim3(2), dim3(768), 0, stream>>>(xp, Whh, bhh, hout);
  k_post<<<dim3(256), dim3(256), 0, stream>>>(hout, cp0, cp1,
                                              o0W, o0b, o0g, o0be,
                                              o1W, o1b, o1g, o1be,
                                              o2W, o2b, o2g, o2be,
                                              ampW, ampb, amps);
  k_synth<<<dim3(256), dim3(256), 0, stream>>>(amps, nbnd, (float*)d_out);
}

// Round 2
// 2179.140 us; speedup vs baseline: 1.1740x; 1.1740x over previous
//
#include <hip/hip_runtime.h>
#include <hip/hip_bf16.h>
#include <math.h>

#define HDIM 128
#define T3   384
#define NT   2048
#define NBND 512
#define NLEN 65536

__device__ __forceinline__ float sigmoidf_(float x){ return 1.f/(1.f+__expf(-x)); }
__device__ __forceinline__ float tanhf_(float x){ float e=__expf(2.f*x); return 1.f - 2.f/(e+1.f); }

// lane ^ 1 within quad (DPP quad_perm [1,0,3,2])
__device__ __forceinline__ float dpp_xor1_(float x){
  int r = __builtin_amdgcn_update_dpp(0, __float_as_int(x), 0xB1, 0xF, 0xF, true);
  return __int_as_float(r);
}
// lane ^ 2 within quad (DPP quad_perm [2,3,0,1])
__device__ __forceinline__ float dpp_xor2_(float x){
  int r = __builtin_amdgcn_update_dpp(0, __float_as_int(x), 0x4E, 0xF, 0xF, true);
  return __int_as_float(r);
}
__device__ __forceinline__ float swz_xor4_(float x){
  return __int_as_float(__builtin_amdgcn_ds_swizzle(__float_as_int(x), 0x101F));
}
__device__ __forceinline__ float swz_xor8_(float x){
  return __int_as_float(__builtin_amdgcn_ds_swizzle(__float_as_int(x), 0x201F));
}
__device__ __forceinline__ void pkfma_(float2& acc, float2 a, float2 b){
  asm("v_pk_fma_f32 %0, %1, %2, %0" : "+v"(acc) : "v"(a), "v"(b));
}

// ---------------------------------------------------------------- in-MLPs
__global__ __launch_bounds__(128) void k_inmlp(
    const float* __restrict__ cp0, const float* __restrict__ cp1,
    const float* __restrict__ W0, const float* __restrict__ b0,
    const float* __restrict__ g0, const float* __restrict__ be0,
    const float* __restrict__ W1, const float* __restrict__ b1,
    const float* __restrict__ g1, const float* __restrict__ be1,
    float* __restrict__ hcat)
{
  int bt = blockIdx.x; int i = threadIdx.x;
  float c0 = cp0[bt], c1 = cp1[bt];
  float v0 = fmaf(c0, W0[i], b0[i]);
  float v1 = fmaf(c1, W1[i], b1[i]);
  __shared__ float red[4];
  float s0 = v0, s1 = v1;
  #pragma unroll
  for (int m=1;m<64;m<<=1){ s0 += __shfl_xor(s0,m); s1 += __shfl_xor(s1,m); }
  if ((i&63)==0){ red[(i>>6)*2+0]=s0; red[(i>>6)*2+1]=s1; }
  __syncthreads();
  float m0 = (red[0]+red[2])*(1.f/128.f);
  float m1 = (red[1]+red[3])*(1.f/128.f);
  __syncthreads();
  float d0 = v0-m0, d1 = v1-m1;
  float q0 = d0*d0, q1 = d1*d1;
  #pragma unroll
  for (int m=1;m<64;m<<=1){ q0 += __shfl_xor(q0,m); q1 += __shfl_xor(q1,m); }
  if ((i&63)==0){ red[(i>>6)*2+0]=q0; red[(i>>6)*2+1]=q1; }
  __syncthreads();
  float va0 = (red[0]+red[2])*(1.f/128.f);
  float va1 = (red[1]+red[3])*(1.f/128.f);
  float y0 = d0*rsqrtf(va0+1e-5f)*g0[i] + be0[i];
  float y1 = d1*rsqrtf(va1+1e-5f)*g1[i] + be1[i];
  y0 = y0>=0.f ? y0 : 0.01f*y0;
  y1 = y1>=0.f ? y1 : 0.01f*y1;
  hcat[(size_t)bt*256 + i]       = y0;
  hcat[(size_t)bt*256 + 128 + i] = y1;
}

// ---------------------------------------------------------------- xp GEMM
// xp[4096][384] = hcat[4096][256] @ Wih^T + bih ; g-major weight rows in LDS
__global__ __launch_bounds__(256) void k_xp(
    const float* __restrict__ hcat, const float* __restrict__ Wih,
    const float* __restrict__ bih, float* __restrict__ xp)
{
  __shared__ float ht[32][260];
  __shared__ float wTg[96][260];
  int mb = blockIdx.x, nbt = blockIdx.y;
  int tid = threadIdx.x;
  int row0 = mb*32, g0 = nbt*96;
  for (int idx = tid; idx < 32*64; idx += 256){
    int t = idx >> 6, q = idx & 63;
    ((float4*)&ht[t][0])[q] = ((const float4*)(hcat + (size_t)(row0+t)*256))[q];
  }
  for (int idx = tid; idx < 96*64; idx += 256){
    int g = idx >> 6, q = idx & 63;
    ((float4*)&wTg[g][0])[q] = ((const float4*)(Wih + (size_t)(g0+g)*256))[q];
  }
  __syncthreads();
  int tt = tid & 7, gg = tid >> 3;
  float a[4][3] = {};
  for (int k=0;k<256;k+=4){
    float4 hv[4], wv[3];
    hv[0] = *(const float4*)&ht[tt][k];
    hv[1] = *(const float4*)&ht[tt+8][k];
    hv[2] = *(const float4*)&ht[tt+16][k];
    hv[3] = *(const float4*)&ht[tt+24][k];
    wv[0] = *(const float4*)&wTg[gg*3+0][k];
    wv[1] = *(const float4*)&wTg[gg*3+1][k];
    wv[2] = *(const float4*)&wTg[gg*3+2][k];
    #pragma unroll
    for (int ti=0;ti<4;ti++){
      #pragma unroll
      for (int gi=0;gi<3;gi++){
        a[ti][gi] = fmaf(hv[ti].x, wv[gi].x, a[ti][gi]);
        a[ti][gi] = fmaf(hv[ti].y, wv[gi].y, a[ti][gi]);
        a[ti][gi] = fmaf(hv[ti].z, wv[gi].z, a[ti][gi]);
        a[ti][gi] = fmaf(hv[ti].w, wv[gi].w, a[ti][gi]);
      }
    }
  }
  #pragma unroll
  for (int ti=0;ti<4;ti++){
    int row = row0 + tt + 8*ti;
    #pragma unroll
    for (int gi=0;gi<3;gi++){
      int g = g0 + gg*3 + gi;
      xp[(size_t)row*T3 + g] = a[ti][gi] + bih[g];
    }
  }
}

// ---------------------------------------------------------------- GRU scan
// 2 blocks (one per batch), 512 threads: thread = (g<64, kh<8).
// 6 Whh rows (g+64i) x 16-k-slice in VGPRs; h slice broadcast from LDS;
// DPP xor1/xor2 + packed ds_swizzle xor4 reduce; gates local; 1 barrier/step.
__global__ __launch_bounds__(512, 2) void k_gru(
    const float* __restrict__ xp, const float* __restrict__ Whh,
    const float* __restrict__ bhh, float* __restrict__ hout)
{
  __shared__ float hbuf[2][128];
  int b = blockIdx.x;
  int tid = threadIdx.x;
  int g  = tid >> 3;     // 0..63
  int kh = tid & 7;      // 0..7, k-slice = kh*16..+15
  float2 w[6][8];
  #pragma unroll
  for (int i=0;i<6;i++){
    const float2* wr = (const float2*)(Whh + (size_t)(g + (i<<6))*HDIM + (kh<<4));
    #pragma unroll
    for (int c=0;c<8;c++) w[i][c] = wr[c];
  }
  int hr = g + ((kh&1)<<6);          // my h row (valid for kh<2)
  float br = bhh[hr], bz = bhh[HDIM+hr], bn = bhh[2*HDIM+hr];
  if (tid < 128) hbuf[0][tid] = 0.f;
  const float* xq = xp + (size_t)b*NT*T3;
  float* hob = hout + (size_t)b*NT*HDIM + hr;
  float ir = xq[hr], iz = xq[HDIM+hr], ixn = xq[2*HDIM+hr];
  float hprev = 0.f;
  __syncthreads();
  int cur = 0;
  for (int t=0;t<NT;t++){
    // prefetch next step's gate inputs (latency hidden under this step)
    float irn=0.f, izn=0.f, ixnn=0.f;
    if (t+1 < NT){
      const float* xn = xq + (size_t)(t+1)*T3;
      irn = xn[hr]; izn = xn[HDIM+hr]; ixnn = xn[2*HDIM+hr];
    }
    const float2* h2 = (const float2*)(&hbuf[cur][kh<<4]);
    float2 a0={0.f,0.f},a1=a0,a2=a0,a3=a0,a4=a0,a5=a0;
    #pragma unroll
    for (int c=0;c<8;c++){
      float2 hv = h2[c];
      pkfma_(a0, w[0][c], hv);
      pkfma_(a1, w[1][c], hv);
      pkfma_(a2, w[2][c], hv);
      pkfma_(a3, w[3][c], hv);
      pkfma_(a4, w[4][c], hv);
      pkfma_(a5, w[5][c], hv);
    }
    float s0=a0.x+a0.y, s1=a1.x+a1.y, s2=a2.x+a2.y,
          s3=a3.x+a3.y, s4=a4.x+a4.y, s5=a5.x+a5.y;
    s0 += dpp_xor1_(s0); s1 += dpp_xor1_(s1); s2 += dpp_xor1_(s2);
    s3 += dpp_xor1_(s3); s4 += dpp_xor1_(s4); s5 += dpp_xor1_(s5);
    s0 += dpp_xor2_(s0); s1 += dpp_xor2_(s1); s2 += dpp_xor2_(s2);
    s3 += dpp_xor2_(s3); s4 += dpp_xor2_(s4); s5 += dpp_xor2_(s5);
    // pack: even kh lanes carry i=0,2,4; odd carry i=1,3,5 -> 3 swizzles
    bool odd = (kh & 1);
    float u0 = odd ? s1 : s0;
    float u1 = odd ? s3 : s2;
    float u2 = odd ? s5 : s4;
    float T0 = u0 + swz_xor4_(u0);   // r-gate row sum
    float T1 = u1 + swz_xor4_(u1);   // z-gate row sum
    float T2 = u2 + swz_xor4_(u2);   // n-gate row sum
    float rr = sigmoidf_(ir + T0 + br);
    float zz = sigmoidf_(iz + T1 + bz);
    float nn = tanhf_(fmaf(rr, T2 + bn, ixn));
    float hn = fmaf(zz, hprev - nn, nn);
    if (kh < 2){
      hbuf[cur^1][hr] = hn;
      hob[(size_t)t*HDIM] = hn;
      hprev = hn;
    }
    __syncthreads();
    cur ^= 1;
    ir = irn; iz = izn; ixn = ixnn;
  }
}

// ---------------------------------------------------------------- post MLPs + amp
// 256 blocks x 16 t. thread = (o = tid>>1, kh = tid&1); weights in VGPRs.
__global__ __launch_bounds__(256, 2) void k_post(
    const float* __restrict__ hout, const float* __restrict__ cp0, const float* __restrict__ cp1,
    const float* __restrict__ o0W, const float* __restrict__ o0b, const float* __restrict__ o0g, const float* __restrict__ o0be,
    const float* __restrict__ o1W, const float* __restrict__ o1b, const float* __restrict__ o1g, const float* __restrict__ o1be,
    const float* __restrict__ o2W, const float* __restrict__ o2b, const float* __restrict__ o2g, const float* __restrict__ o2be,
    const float* __restrict__ ampW, const float* __restrict__ ampb,
    float* __restrict__ amps)
{
  __shared__ float A[16][136];
  __shared__ float Bf[16][136];
  __shared__ float lng[128], lnb[128];
  int blk = blockIdx.x;
  int b = blk >> 7, tc = blk & 127;
  int bt0 = b*NT + tc*16;
  int tid = threadIdx.x;
  int kh = tid & 1, o = tid >> 1;
  for (int idx = tid; idx < 16*32; idx += 256){
    int t = idx >> 5, q = idx & 31;
    ((float4*)&A[t][0])[q] = ((const float4*)(hout + (size_t)(bt0+t)*HDIM))[q];
  }
  if (tid < 16){
    int bt = bt0 + tid;
    A[tid][128] = cp0[bt]; A[tid][129] = cp1[bt];
    #pragma unroll
    for (int z=130; z<136; z++){ A[tid][z] = 0.f; Bf[tid][z] = 0.f; }
    Bf[tid][128] = 0.f; Bf[tid][129] = 0.f;
  }
  __syncthreads();
  const float* Ws[3] = {o0W, o1W, o2W};
  const float* Bs[3] = {o0b, o1b, o2b};
  const float* Gs[3] = {o0g, o1g, o2g};
  const float* Es[3] = {o0be, o1be, o2be};
  const int kds[3] = {130, 128, 128};
  float (*src)[136] = A;
  float (*dst)[136] = Bf;
  for (int l=0; l<3; l++){
    const int kd = kds[l];
    const float* W = Ws[l];
    if (tid < 128){ lng[tid] = Gs[l][tid]; lnb[tid] = Es[l][tid]; }
    float w[68];
    #pragma unroll
    for (int c=0;c<68;c++){
      int k = kh*68 + c;
      w[c] = (k < kd) ? W[(size_t)o*kd + k] : 0.f;
    }
    float bias = (kh==0) ? Bs[l][o] : 0.f;
    float acc16[16];
    #pragma unroll
    for (int t=0;t<16;t++){
      float acc = bias;
      const float* ar = &src[t][kh*68];
      #pragma unroll
      for (int c=0;c<68;c++) acc = fmaf(w[c], ar[c], acc);
      acc16[t] = acc;
    }
    #pragma unroll
    for (int t=0;t<16;t++) acc16[t] += dpp_xor1_(acc16[t]);
    if (kh==0){
      #pragma unroll
      for (int t=0;t<16;t++) dst[t][o] = acc16[t];
    }
    __syncthreads();
    {
      int t = tid >> 4, j = tid & 15;
      float4 v0 = ((float4*)&dst[t][0])[j*2];
      float4 v1 = ((float4*)&dst[t][0])[j*2+1];
      float sm = v0.x+v0.y+v0.z+v0.w + v1.x+v1.y+v1.z+v1.w;
      float sq = v0.x*v0.x+v0.y*v0.y+v0.z*v0.z+v0.w*v0.w
               + v1.x*v1.x+v1.y*v1.y+v1.z*v1.z+v1.w*v1.w;
      sm += dpp_xor1_(sm); sq += dpp_xor1_(sq);
      sm += dpp_xor2_(sm); sq += dpp_xor2_(sq);
      sm += swz_xor4_(sm); sq += swz_xor4_(sq);
      sm += swz_xor8_(sm); sq += swz_xor8_(sq);
      float mean = sm * (1.f/128.f);
      float var  = sq * (1.f/128.f) - mean*mean;
      float rs = rsqrtf(var + 1e-5f);
      float o8[8] = {v0.x,v0.y,v0.z,v0.w,v1.x,v1.y,v1.z,v1.w};
      #pragma unroll
      for (int e=0;e<8;e++){
        int oc = j*8+e;
        float y = (o8[e]-mean)*rs*lng[oc] + lnb[oc];
        o8[e] = y>=0.f ? y : 0.01f*y;
      }
      ((float4*)&dst[t][0])[j*2]   = make_float4(o8[0],o8[1],o8[2],o8[3]);
      ((float4*)&dst[t][0])[j*2+1] = make_float4(o8[4],o8[5],o8[6],o8[7]);
    }
    __syncthreads();
    { float (*tmp)[136] = src; src = dst; dst = tmp; }
  }
  // amp projection 128 -> 512 + scale function
  #pragma unroll 1
  for (int ch=0; ch<4; ch++){
    int oc = ch*128 + o;
    float w[68];
    #pragma unroll
    for (int c=0;c<68;c++){
      int k = kh*68 + c;
      w[c] = (k < 128) ? ampW[(size_t)oc*HDIM + k] : 0.f;
    }
    float bias = (kh==0) ? ampb[oc] : 0.f;
    #pragma unroll
    for (int t=0;t<16;t++){
      float acc = bias;
      const float* ar = &src[t][kh*68];
      #pragma unroll
      for (int c=0;c<68;c++) acc = fmaf(w[c], ar[c], acc);
      acc += dpp_xor1_(acc);
      if (kh==0){
        float sg = sigmoidf_(acc);
        float p = __powf(sg, 2.3025850929940457f);
        amps[(size_t)(bt0+t)*NBND + oc] = 2.f*p + 1e-18f;
      }
    }
  }
}

// ---------------------------------------------------------------- synth mixdown
__global__ __launch_bounds__(256) void k_synth(
    const float* __restrict__ amps, const float* __restrict__ nbands,
    float* __restrict__ out)
{
  __shared__ float SA[2*10*516];
  int blk = blockIdx.x;
  int tid = threadIdx.x;
  int s = blk*256 + tid;
  int tbase = blk*8 - 1; if (tbase < 0) tbase = 0;
  for (int idx = tid; idx < 2*10*128; idx += 256){
    int bb  = idx / 1280;
    int rem = idx - bb*1280;
    int ttl = rem >> 7;
    int q   = rem & 127;
    int tg = tbase + ttl; if (tg > NT-1) tg = NT-1;
    ((float4*)&SA[bb*5160 + ttl*516])[q] =
        ((const float4*)(amps + (size_t)(bb*NT + tg)*NBND))[q];
  }
  __syncthreads();
  float srcp = fmaxf((s + 0.5f)*(1.f/32.f) - 0.5f, 0.f);
  int i0 = (int)srcp;
  float w = srcp - (float)i0;
  int i1 = i0 + 1; if (i1 > NT-1) i1 = NT-1;
  int l0 = i0 - tbase, l1 = i1 - tbase;
  const float4* A0 = (const float4*)(SA + l0*516);
  const float4* A1 = (const float4*)(SA + l1*516);
  const float4* B0 = (const float4*)(SA + 5160 + l0*516);
  const float4* B1 = (const float4*)(SA + 5160 + l1*516);
  float acc0 = 0.f, acc1 = 0.f;
  const float* nb = nbands + s;
  for (int c4=0;c4<128;c4++){
    float4 a0v = A0[c4], a1v = A1[c4], b0v = B0[c4], b1v = B1[c4];
    size_t cb = (size_t)(c4*4)*NLEN;
    float n0 = nb[cb], n1 = nb[cb+(size_t)NLEN], n2 = nb[cb+2*(size_t)NLEN], n3 = nb[cb+3*(size_t)NLEN];
    acc0 = fmaf(fmaf(w, a1v.x - a0v.x, a0v.x), n0, acc0);
    acc0 = fmaf(fmaf(w, a1v.y - a0v.y, a0v.y), n1, acc0);
    acc0 = fmaf(fmaf(w, a1v.z - a0v.z, a0v.z), n2, acc0);
    acc0 = fmaf(fmaf(w, a1v.w - a0v.w, a0v.w), n3, acc0);
    acc1 = fmaf(fmaf(w, b1v.x - b0v.x, b0v.x), n0, acc1);
    acc1 = fmaf(fmaf(w, b1v.y - b0v.y, b0v.y), n1, acc1);
    acc1 = fmaf(fmaf(w, b1v.z - b0v.z, b0v.z), n2, acc1);
    acc1 = fmaf(fmaf(w, b1v.w - b0v.w, b0v.w), n3, acc1);
  }
  out[s]        = acc0;
  out[NLEN + s] = acc1;
}

// ----------------------------------------------------------------
extern "C" void kernel_launch(void* const* d_in, const int* in_sizes, int n_in,
                              void* d_out, int out_size, void* d_ws, size_t ws_size,
                              hipStream_t stream)
{
  const float* cp0   = (const float*)d_in[0];
  const float* cp1   = (const float*)d_in[1];
  const float* in0W  = (const float*)d_in[2];
  const float* in0b  = (const float*)d_in[3];
  const float* in0g  = (const float*)d_in[4];
  const float* in0be = (const float*)d_in[5];
  const float* in1W  = (const float*)d_in[6];
  const float* in1b  = (const float*)d_in[7];
  const float* in1g  = (const float*)d_in[8];
  const float* in1be = (const float*)d_in[9];
  const float* Wih   = (const float*)d_in[10];
  const float* Whh   = (const float*)d_in[11];
  const float* bih   = (const float*)d_in[12];
  const float* bhh   = (const float*)d_in[13];
  const float* o0W = (const float*)d_in[14]; const float* o0b = (const float*)d_in[15];
  const float* o0g = (const float*)d_in[16]; const float* o0be = (const float*)d_in[17];
  const float* o1W = (const float*)d_in[18]; const float* o1b = (const float*)d_in[19];
  const float* o1g = (const float*)d_in[20]; const float* o1be = (const float*)d_in[21];
  const float* o2W = (const float*)d_in[22]; const float* o2b = (const float*)d_in[23];
  const float* o2g = (const float*)d_in[24]; const float* o2be = (const float*)d_in[25];
  const float* ampW = (const float*)d_in[26];
  const float* ampb = (const float*)d_in[27];
  const float* nbnd = (const float*)d_in[28];

  float* ws   = (float*)d_ws;
  float* hcat = ws;                       // 4096*256
  float* xp   = hcat + 4096*256;          // 4096*384
  float* hout = xp   + 4096*384;          // 4096*128
  float* amps = hout + 4096*128;          // 4096*512

  k_inmlp<<<dim3(4096), dim3(128), 0, stream>>>(cp0, cp1, in0W, in0b, in0g, in0be,
                                                in1W, in1b, in1g, in1be, hcat);
  k_xp<<<dim3(128,4), dim3(256), 0, stream>>>(hcat, Wih, bih, xp);
  k_gru<<<dim3(2), dim3(512), 0, stream>>>(xp, Whh, bhh, hout);
  k_post<<<dim3(256), dim3(256), 0, stream>>>(hout, cp0, cp1,
                                              o0W, o0b, o0g, o0be,
                                              o1W, o1b, o1g, o1be,
                                              o2W, o2b, o2g, o2be,
                                              ampW, ampb, amps);
  k_synth<<<dim3(256), dim3(256), 0, stream>>>(amps, nbnd, (float*)d_out);
}

// Round 3
// 1758.957 us; speedup vs baseline: 1.4544x; 1.2389x over previous
//
#include <hip/hip_runtime.h>
#include <hip/hip_bf16.h>
#include <math.h>

#define HDIM 128
#define T3   384
#define NT   2048
#define NBND 512
#define NLEN 65536

__device__ __forceinline__ float sigmoidf_(float x){ return 1.f/(1.f+__expf(-x)); }
__device__ __forceinline__ float tanhf_(float x){ float e=__expf(2.f*x); return 1.f - 2.f/(e+1.f); }

// lane ^ 1 within quad (DPP quad_perm [1,0,3,2])
__device__ __forceinline__ float dpp_xor1_(float x){
  int r = __builtin_amdgcn_update_dpp(0, __float_as_int(x), 0xB1, 0xF, 0xF, true);
  return __int_as_float(r);
}
// lane ^ 2 within quad (DPP quad_perm [2,3,0,1])
__device__ __forceinline__ float dpp_xor2_(float x){
  int r = __builtin_amdgcn_update_dpp(0, __float_as_int(x), 0x4E, 0xF, 0xF, true);
  return __int_as_float(r);
}
// ROW_HALF_MIRROR: lane ^ 7 within each 8-lane half-row (VALU, not LDS)
__device__ __forceinline__ float dpp_xor7_(float x){
  int r = __builtin_amdgcn_update_dpp(0, __float_as_int(x), 0x141, 0xF, 0xF, true);
  return __int_as_float(r);
}
__device__ __forceinline__ float swz_xor4_(float x){
  return __int_as_float(__builtin_amdgcn_ds_swizzle(__float_as_int(x), 0x101F));
}
__device__ __forceinline__ float swz_xor8_(float x){
  return __int_as_float(__builtin_amdgcn_ds_swizzle(__float_as_int(x), 0x201F));
}
__device__ __forceinline__ void pkfma_(float2& acc, float2 a, float2 b){
  asm("v_pk_fma_f32 %0, %1, %2, %0" : "+v"(acc) : "v"(a), "v"(b));
}

// ---------------------------------------------------------------- in-MLPs
__global__ __launch_bounds__(128) void k_inmlp(
    const float* __restrict__ cp0, const float* __restrict__ cp1,
    const float* __restrict__ W0, const float* __restrict__ b0,
    const float* __restrict__ g0, const float* __restrict__ be0,
    const float* __restrict__ W1, const float* __restrict__ b1,
    const float* __restrict__ g1, const float* __restrict__ be1,
    float* __restrict__ hcat)
{
  int bt = blockIdx.x; int i = threadIdx.x;
  float c0 = cp0[bt], c1 = cp1[bt];
  float v0 = fmaf(c0, W0[i], b0[i]);
  float v1 = fmaf(c1, W1[i], b1[i]);
  __shared__ float red[4];
  float s0 = v0, s1 = v1;
  #pragma unroll
  for (int m=1;m<64;m<<=1){ s0 += __shfl_xor(s0,m); s1 += __shfl_xor(s1,m); }
  if ((i&63)==0){ red[(i>>6)*2+0]=s0; red[(i>>6)*2+1]=s1; }
  __syncthreads();
  float m0 = (red[0]+red[2])*(1.f/128.f);
  float m1 = (red[1]+red[3])*(1.f/128.f);
  __syncthreads();
  float d0 = v0-m0, d1 = v1-m1;
  float q0 = d0*d0, q1 = d1*d1;
  #pragma unroll
  for (int m=1;m<64;m<<=1){ q0 += __shfl_xor(q0,m); q1 += __shfl_xor(q1,m); }
  if ((i&63)==0){ red[(i>>6)*2+0]=q0; red[(i>>6)*2+1]=q1; }
  __syncthreads();
  float va0 = (red[0]+red[2])*(1.f/128.f);
  float va1 = (red[1]+red[3])*(1.f/128.f);
  float y0 = d0*rsqrtf(va0+1e-5f)*g0[i] + be0[i];
  float y1 = d1*rsqrtf(va1+1e-5f)*g1[i] + be1[i];
  y0 = y0>=0.f ? y0 : 0.01f*y0;
  y1 = y1>=0.f ? y1 : 0.01f*y1;
  hcat[(size_t)bt*256 + i]       = y0;
  hcat[(size_t)bt*256 + 128 + i] = y1;
}

// ---------------------------------------------------------------- xp GEMM
__global__ __launch_bounds__(256) void k_xp(
    const float* __restrict__ hcat, const float* __restrict__ Wih,
    const float* __restrict__ bih, float* __restrict__ xp)
{
  __shared__ float ht[32][260];
  __shared__ float wTg[96][260];
  int mb = blockIdx.x, nbt = blockIdx.y;
  int tid = threadIdx.x;
  int row0 = mb*32, g0 = nbt*96;
  for (int idx = tid; idx < 32*64; idx += 256){
    int t = idx >> 6, q = idx & 63;
    ((float4*)&ht[t][0])[q] = ((const float4*)(hcat + (size_t)(row0+t)*256))[q];
  }
  for (int idx = tid; idx < 96*64; idx += 256){
    int g = idx >> 6, q = idx & 63;
    ((float4*)&wTg[g][0])[q] = ((const float4*)(Wih + (size_t)(g0+g)*256))[q];
  }
  __syncthreads();
  int tt = tid & 7, gg = tid >> 3;
  float a[4][3] = {};
  for (int k=0;k<256;k+=4){
    float4 hv[4], wv[3];
    hv[0] = *(const float4*)&ht[tt][k];
    hv[1] = *(const float4*)&ht[tt+8][k];
    hv[2] = *(const float4*)&ht[tt+16][k];
    hv[3] = *(const float4*)&ht[tt+24][k];
    wv[0] = *(const float4*)&wTg[gg*3+0][k];
    wv[1] = *(const float4*)&wTg[gg*3+1][k];
    wv[2] = *(const float4*)&wTg[gg*3+2][k];
    #pragma unroll
    for (int ti=0;ti<4;ti++){
      #pragma unroll
      for (int gi=0;gi<3;gi++){
        a[ti][gi] = fmaf(hv[ti].x, wv[gi].x, a[ti][gi]);
        a[ti][gi] = fmaf(hv[ti].y, wv[gi].y, a[ti][gi]);
        a[ti][gi] = fmaf(hv[ti].z, wv[gi].z, a[ti][gi]);
        a[ti][gi] = fmaf(hv[ti].w, wv[gi].w, a[ti][gi]);
      }
    }
  }
  #pragma unroll
  for (int ti=0;ti<4;ti++){
    int row = row0 + tt + 8*ti;
    #pragma unroll
    for (int gi=0;gi<3;gi++){
      int g = g0 + gg*3 + gi;
      xp[(size_t)row*T3 + g] = a[ti][gi] + bih[g];
    }
  }
}

// ---------------------------------------------------------------- GRU scan
// 2 blocks x 512 threads; thread = (g<64, kh<8). 6 Whh rows x 16-k in VGPRs.
// h slices in padded LDS [8][20] -> 4x ds_read_b128 conflict-free.
// k-reduce = DPP xor1/xor2/half-mirror (pure VALU). 1 barrier/step.
__global__ __launch_bounds__(512) void k_gru(
    const float* __restrict__ xp, const float* __restrict__ Whh,
    const float* __restrict__ bhh, float* __restrict__ hout)
{
  __shared__ float hbuf[2][8][20];   // padded: slice kh at word kh*20
  int b = blockIdx.x;
  int tid = threadIdx.x;
  int g  = tid >> 3;     // 0..63
  int kh = tid & 7;      // 0..7, k-slice = kh*16..+15
  float2 w[6][8];
  #pragma unroll
  for (int i=0;i<6;i++){
    const float2* wr = (const float2*)(Whh + (size_t)(g + (i<<6))*HDIM + (kh<<4));
    #pragma unroll
    for (int c=0;c<8;c++) w[i][c] = wr[c];
  }
  int par = kh & 1;
  int hr = g + (par<<6);
  float br = bhh[hr], bz = bhh[HDIM+hr], bn = bhh[2*HDIM+hr];
  if (tid < 128) hbuf[0][tid>>4][tid&15] = 0.f;
  const float* xq = xp + (size_t)b*NT*T3;
  float* hob = hout + (size_t)b*NT*HDIM + hr;
  float ir = xq[hr], iz = xq[HDIM+hr], ixn = xq[2*HDIM+hr];
  float hprev = 0.f;
  __syncthreads();
  int cur = 0;
  for (int t=0;t<NT;t++){
    // prefetch next step's gate inputs
    float irn=0.f, izn=0.f, ixnn=0.f;
    if (t+1 < NT){
      const float* xn = xq + (size_t)(t+1)*T3;
      irn = xn[hr]; izn = xn[HDIM+hr]; ixnn = xn[2*HDIM+hr];
    }
    const float4* hsl = (const float4*)&hbuf[cur][kh][0];
    float4 hv0 = hsl[0], hv1 = hsl[1], hv2 = hsl[2], hv3 = hsl[3];
    float2 h2[8];
    h2[0] = make_float2(hv0.x, hv0.y); h2[1] = make_float2(hv0.z, hv0.w);
    h2[2] = make_float2(hv1.x, hv1.y); h2[3] = make_float2(hv1.z, hv1.w);
    h2[4] = make_float2(hv2.x, hv2.y); h2[5] = make_float2(hv2.z, hv2.w);
    h2[6] = make_float2(hv3.x, hv3.y); h2[7] = make_float2(hv3.z, hv3.w);
    float2 a0={0.f,0.f},a1=a0,a2=a0,a3=a0,a4=a0,a5=a0;
    #pragma unroll
    for (int c=0;c<8;c++){
      float2 hv = h2[c];
      pkfma_(a0, w[0][c], hv);
      pkfma_(a1, w[1][c], hv);
      pkfma_(a2, w[2][c], hv);
      pkfma_(a3, w[3][c], hv);
      pkfma_(a4, w[4][c], hv);
      pkfma_(a5, w[5][c], hv);
    }
    float s0=a0.x+a0.y, s1=a1.x+a1.y, s2=a2.x+a2.y,
          s3=a3.x+a3.y, s4=a4.x+a4.y, s5=a5.x+a5.y;
    s0 += dpp_xor1_(s0); s1 += dpp_xor1_(s1); s2 += dpp_xor1_(s2);
    s3 += dpp_xor1_(s3); s4 += dpp_xor1_(s4); s5 += dpp_xor1_(s5);
    s0 += dpp_xor2_(s0); s1 += dpp_xor2_(s1); s2 += dpp_xor2_(s2);
    s3 += dpp_xor2_(s3); s4 += dpp_xor2_(s4); s5 += dpp_xor2_(s5);
    s0 += dpp_xor7_(s0); s1 += dpp_xor7_(s1); s2 += dpp_xor7_(s2);
    s3 += dpp_xor7_(s3); s4 += dpp_xor7_(s4); s5 += dpp_xor7_(s5);
    float T0 = par ? s1 : s0;   // r row-sum for hr
    float T1 = par ? s3 : s2;   // z
    float T2 = par ? s5 : s4;   // n
    float rr = sigmoidf_(ir + T0 + br);
    float zz = sigmoidf_(iz + T1 + bz);
    float nn = tanhf_(fmaf(rr, T2 + bn, ixn));
    float hn = fmaf(zz, hprev - nn, nn);
    hprev = hn;
    if (kh < 2){
      hbuf[cur^1][hr>>4][hr&15] = hn;
      hob[(size_t)t*HDIM] = hn;
    }
    __syncthreads();
    cur ^= 1;
    ir = irn; iz = izn; ixn = ixnn;
  }
}

// ---------------------------------------------------------------- post MLPs + amp
// 512 blocks x 8 t. thread = (o = tid>>1, kh = tid&1); weights in VGPRs,
// activations via float4 LDS reads; 2 blocks/CU.
__global__ __launch_bounds__(256, 2) void k_post(
    const float* __restrict__ hout, const float* __restrict__ cp0, const float* __restrict__ cp1,
    const float* __restrict__ o0W, const float* __restrict__ o0b, const float* __restrict__ o0g, const float* __restrict__ o0be,
    const float* __restrict__ o1W, const float* __restrict__ o1b, const float* __restrict__ o1g, const float* __restrict__ o1be,
    const float* __restrict__ o2W, const float* __restrict__ o2b, const float* __restrict__ o2g, const float* __restrict__ o2be,
    const float* __restrict__ ampW, const float* __restrict__ ampb,
    float* __restrict__ amps)
{
  __shared__ float A[8][136];
  __shared__ float Bf[8][136];
  __shared__ float lng[128], lnb[128];
  int blk = blockIdx.x;            // 0..511
  int b = blk >> 8, tc = blk & 255;
  int bt0 = b*NT + tc*8;
  int tid = threadIdx.x;
  int kh = tid & 1, o = tid >> 1;
  {
    int t = tid >> 5, q = tid & 31;
    ((float4*)&A[t][0])[q] = ((const float4*)(hout + (size_t)(bt0+t)*HDIM))[q];
  }
  if (tid < 8){
    int bt = bt0 + tid;
    A[tid][128] = cp0[bt]; A[tid][129] = cp1[bt];
    #pragma unroll
    for (int z=130; z<136; z++){ A[tid][z] = 0.f; Bf[tid][z] = 0.f; }
    Bf[tid][128] = 0.f; Bf[tid][129] = 0.f;
  }
  __syncthreads();
  const float* Ws[3] = {o0W, o1W, o2W};
  const float* Bs[3] = {o0b, o1b, o2b};
  const float* Gs[3] = {o0g, o1g, o2g};
  const float* Es[3] = {o0be, o1be, o2be};
  const int kds[3] = {130, 128, 128};
  float (*src)[136] = A;
  float (*dst)[136] = Bf;
  for (int l=0; l<3; l++){
    const int kd = kds[l];
    const float* W = Ws[l];
    if (tid < 128){ lng[tid] = Gs[l][tid]; lnb[tid] = Es[l][tid]; }
    float w[68];
    #pragma unroll
    for (int c=0;c<68;c++){
      int k = kh*68 + c;
      w[c] = (k < kd) ? W[(size_t)o*kd + k] : 0.f;
    }
    float bias = (kh==0) ? Bs[l][o] : 0.f;
    float acc8[8];
    #pragma unroll
    for (int t=0;t<8;t++){
      const float4* ar4 = (const float4*)&src[t][kh*68];
      float acc = bias, acc2 = 0.f;
      #pragma unroll
      for (int c4=0;c4<17;c4++){
        float4 av = ar4[c4];
        acc  = fmaf(w[c4*4+0], av.x, acc);
        acc2 = fmaf(w[c4*4+1], av.y, acc2);
        acc  = fmaf(w[c4*4+2], av.z, acc);
        acc2 = fmaf(w[c4*4+3], av.w, acc2);
      }
      acc8[t] = acc + acc2;
    }
    #pragma unroll
    for (int t=0;t<8;t++) acc8[t] += dpp_xor1_(acc8[t]);
    if (kh==0){
      #pragma unroll
      for (int t=0;t<8;t++) dst[t][o] = acc8[t];
    }
    __syncthreads();
    if (tid < 128){
      int t = tid >> 4, j = tid & 15;
      float4 v0 = ((float4*)&dst[t][0])[j*2];
      float4 v1 = ((float4*)&dst[t][0])[j*2+1];
      float sm = v0.x+v0.y+v0.z+v0.w + v1.x+v1.y+v1.z+v1.w;
      float sq = v0.x*v0.x+v0.y*v0.y+v0.z*v0.z+v0.w*v0.w
               + v1.x*v1.x+v1.y*v1.y+v1.z*v1.z+v1.w*v1.w;
      sm += dpp_xor1_(sm); sq += dpp_xor1_(sq);
      sm += dpp_xor2_(sm); sq += dpp_xor2_(sq);
      sm += swz_xor4_(sm); sq += swz_xor4_(sq);
      sm += swz_xor8_(sm); sq += swz_xor8_(sq);
      float mean = sm * (1.f/128.f);
      float var  = sq * (1.f/128.f) - mean*mean;
      float rs = rsqrtf(var + 1e-5f);
      float o8[8] = {v0.x,v0.y,v0.z,v0.w,v1.x,v1.y,v1.z,v1.w};
      #pragma unroll
      for (int e=0;e<8;e++){
        int oc = j*8+e;
        float y = (o8[e]-mean)*rs*lng[oc] + lnb[oc];
        o8[e] = y>=0.f ? y : 0.01f*y;
      }
      ((float4*)&dst[t][0])[j*2]   = make_float4(o8[0],o8[1],o8[2],o8[3]);
      ((float4*)&dst[t][0])[j*2+1] = make_float4(o8[4],o8[5],o8[6],o8[7]);
    }
    __syncthreads();
    { float (*tmp)[136] = src; src = dst; dst = tmp; }
  }
  // amp projection 128 -> 512 + scale function
  #pragma unroll 1
  for (int ch=0; ch<4; ch++){
    int oc = ch*128 + o;
    float w[68];
    #pragma unroll
    for (int c=0;c<68;c++){
      int k = kh*68 + c;
      w[c] = (k < 128) ? ampW[(size_t)oc*HDIM + k] : 0.f;
    }
    float bias = (kh==0) ? ampb[oc] : 0.f;
    #pragma unroll
    for (int t=0;t<8;t++){
      const float4* ar4 = (const float4*)&src[t][kh*68];
      float acc = bias, acc2 = 0.f;
      #pragma unroll
      for (int c4=0;c4<17;c4++){
        float4 av = ar4[c4];
        acc  = fmaf(w[c4*4+0], av.x, acc);
        acc2 = fmaf(w[c4*4+1], av.y, acc2);
        acc  = fmaf(w[c4*4+2], av.z, acc);
        acc2 = fmaf(w[c4*4+3], av.w, acc2);
      }
      acc = acc + acc2;
      acc += dpp_xor1_(acc);
      if (kh==0){
        float sg = sigmoidf_(acc);
        float p = __powf(sg, 2.3025850929940457f);
        amps[(size_t)(bt0+t)*NBND + oc] = 2.f*p + 1e-18f;
      }
    }
  }
}

// ---------------------------------------------------------------- synth mixdown
__global__ __launch_bounds__(256) void k_synth(
    const float* __restrict__ amps, const float* __restrict__ nbands,
    float* __restrict__ out)
{
  __shared__ float SA[2*10*516];
  int blk = blockIdx.x;
  int tid = threadIdx.x;
  int s = blk*256 + tid;
  int tbase = blk*8 - 1; if (tbase < 0) tbase = 0;
  for (int idx = tid; idx < 2*10*128; idx += 256){
    int bb  = idx / 1280;
    int rem = idx - bb*1280;
    int ttl = rem >> 7;
    int q   = rem & 127;
    int tg = tbase + ttl; if (tg > NT-1) tg = NT-1;
    ((float4*)&SA[bb*5160 + ttl*516])[q] =
        ((const float4*)(amps + (size_t)(bb*NT + tg)*NBND))[q];
  }
  __syncthreads();
  float srcp = fmaxf((s + 0.5f)*(1.f/32.f) - 0.5f, 0.f);
  int i0 = (int)srcp;
  float w = srcp - (float)i0;
  int i1 = i0 + 1; if (i1 > NT-1) i1 = NT-1;
  int l0 = i0 - tbase, l1 = i1 - tbase;
  const float4* A0 = (const float4*)(SA + l0*516);
  const float4* A1 = (const float4*)(SA + l1*516);
  const float4* B0 = (const float4*)(SA + 5160 + l0*516);
  const float4* B1 = (const float4*)(SA + 5160 + l1*516);
  float acc0 = 0.f, acc1 = 0.f;
  const float* nb = nbands + s;
  for (int c4=0;c4<128;c4++){
    float4 a0v = A0[c4], a1v = A1[c4], b0v = B0[c4], b1v = B1[c4];
    size_t cb = (size_t)(c4*4)*NLEN;
    float n0 = nb[cb], n1 = nb[cb+(size_t)NLEN], n2 = nb[cb+2*(size_t)NLEN], n3 = nb[cb+3*(size_t)NLEN];
    acc0 = fmaf(fmaf(w, a1v.x - a0v.x, a0v.x), n0, acc0);
    acc0 = fmaf(fmaf(w, a1v.y - a0v.y, a0v.y), n1, acc0);
    acc0 = fmaf(fmaf(w, a1v.z - a0v.z, a0v.z), n2, acc0);
    acc0 = fmaf(fmaf(w, a1v.w - a0v.w, a0v.w), n3, acc0);
    acc1 = fmaf(fmaf(w, b1v.x - b0v.x, b0v.x), n0, acc1);
    acc1 = fmaf(fmaf(w, b1v.y - b0v.y, b0v.y), n1, acc1);
    acc1 = fmaf(fmaf(w, b1v.z - b0v.z, b0v.z), n2, acc1);
    acc1 = fmaf(fmaf(w, b1v.w - b0v.w, b0v.w), n3, acc1);
  }
  out[s]        = acc0;
  out[NLEN + s] = acc1;
}

// ----------------------------------------------------------------
extern "C" void kernel_launch(void* const* d_in, const int* in_sizes, int n_in,
                              void* d_out, int out_size, void* d_ws, size_t ws_size,
                              hipStream_t stream)
{
  const float* cp0   = (const float*)d_in[0];
  const float* cp1   = (const float*)d_in[1];
  const float* in0W  = (const float*)d_in[2];
  const float* in0b  = (const float*)d_in[3];
  const float* in0g  = (const float*)d_in[4];
  const float* in0be = (const float*)d_in[5];
  const float* in1W  = (const float*)d_in[6];
  const float* in1b  = (const float*)d_in[7];
  const float* in1g  = (const float*)d_in[8];
  const float* in1be = (const float*)d_in[9];
  const float* Wih   = (const float*)d_in[10];
  const float* Whh   = (const float*)d_in[11];
  const float* bih   = (const float*)d_in[12];
  const float* bhh   = (const float*)d_in[13];
  const float* o0W = (const float*)d_in[14]; const float* o0b = (const float*)d_in[15];
  const float* o0g = (const float*)d_in[16]; const float* o0be = (const float*)d_in[17];
  const float* o1W = (const float*)d_in[18]; const float* o1b = (const float*)d_in[19];
  const float* o1g = (const float*)d_in[20]; const float* o1be = (const float*)d_in[21];
  const float* o2W = (const float*)d_in[22]; const float* o2b = (const float*)d_in[23];
  const float* o2g = (const float*)d_in[24]; const float* o2be = (const float*)d_in[25];
  const float* ampW = (const float*)d_in[26];
  const float* ampb = (const float*)d_in[27];
  const float* nbnd = (const float*)d_in[28];

  float* ws   = (float*)d_ws;
  float* hcat = ws;                       // 4096*256
  float* xp   = hcat + 4096*256;          // 4096*384
  float* hout = xp   + 4096*384;          // 4096*128
  float* amps = hout + 4096*128;          // 4096*512

  k_inmlp<<<dim3(4096), dim3(128), 0, stream>>>(cp0, cp1, in0W, in0b, in0g, in0be,
                                                in1W, in1b, in1g, in1be, hcat);
  k_xp<<<dim3(128,4), dim3(256), 0, stream>>>(hcat, Wih, bih, xp);
  k_gru<<<dim3(2), dim3(512), 0, stream>>>(xp, Whh, bhh, hout);
  k_post<<<dim3(512), dim3(256), 0, stream>>>(hout, cp0, cp1,
                                              o0W, o0b, o0g, o0be,
                                              o1W, o1b, o1g, o1be,
                                              o2W, o2b, o2g, o2be,
                                              ampW, ampb, amps);
  k_synth<<<dim3(256), dim3(256), 0, stream>>>(amps, nbnd, (float*)d_out);
}